// Round 1
// baseline (1695.865 us; speedup 1.0000x reference)
//
#include <hip/hip_runtime.h>

#define DEGREE 10
#define NSTEP 9

// One thread processes 2 nodes (nA, nB = nA+256). fp32 VALU throughout.
// U reads are wave-uniform -> expect s_load scalarization (check disasm).
__global__ __launch_bounds__(256, 4) void tt_kernel(
    const float* __restrict__ ns,   // (n, 10, 16)
    const float* __restrict__ U0,   // (16, 16)
    const float* __restrict__ Ur,   // (9, 16, 16, 16)
    const float* __restrict__ Uo,   // (16, 16)
    float* __restrict__ out,        // (n, 16)
    int n)
{
    const int base = blockIdx.x * 512 + threadIdx.x;
    const int nA = base;
    const int nB = base + 256;
    const int cA = (nA < n) ? nA : 0;   // clamp for safe (discarded) reads
    const int cB = (nB < n) ? nB : 0;
    const float* gA = ns + (size_t)cA * (DEGREE * 16);
    const float* gB = ns + (size_t)cB * (DEGREE * 16);

    float rA[16], rB[16];

    // ---- stage 0: ris0[c] = sum_b U0[b,c] * h0[b] ----
    {
        float hA[16], hB[16];
#pragma unroll
        for (int i = 0; i < 4; ++i) {
            float4 a = ((const float4*)gA)[i];
            float4 b = ((const float4*)gB)[i];
            hA[4*i+0] = a.x; hA[4*i+1] = a.y; hA[4*i+2] = a.z; hA[4*i+3] = a.w;
            hB[4*i+0] = b.x; hB[4*i+1] = b.y; hB[4*i+2] = b.z; hB[4*i+3] = b.w;
        }
#pragma unroll
        for (int c = 0; c < 16; ++c) { rA[c] = 0.f; rB[c] = 0.f; }
#pragma unroll
        for (int b = 0; b < 16; ++b) {
#pragma unroll
            for (int c4 = 0; c4 < 4; ++c4) {
                float4 u = ((const float4*)(U0 + b * 16))[c4];
                rA[4*c4+0] += u.x * hA[b]; rA[4*c4+1] += u.y * hA[b];
                rA[4*c4+2] += u.z * hA[b]; rA[4*c4+3] += u.w * hA[b];
                rB[4*c4+0] += u.x * hB[b]; rB[4*c4+1] += u.y * hB[b];
                rB[4*c4+2] += u.z * hB[b]; rB[4*c4+3] += u.w * hB[b];
            }
        }
    }

    // ---- 9 bilinear steps: s[c] = sum_{a,b} Ut[a,b,c] * r[a] * h[b] ----
#pragma unroll 1
    for (int t = 0; t < NSTEP; ++t) {
        const float* Ut = Ur + t * 4096;
        const float4* hpA = (const float4*)(gA + (t + 1) * 16);
        const float4* hpB = (const float4*)(gB + (t + 1) * 16);
        float sA[16], sB[16];
#pragma unroll
        for (int c = 0; c < 16; ++c) { sA[c] = 0.f; sB[c] = 0.f; }
        // b-loop rolled in chunks of 4 to keep code size < L1I
#pragma unroll 1
        for (int bc = 0; bc < 4; ++bc) {
            float4 hvA = hpA[bc];
            float4 hvB = hpB[bc];
            float hAj[4] = {hvA.x, hvA.y, hvA.z, hvA.w};
            float hBj[4] = {hvB.x, hvB.y, hvB.z, hvB.w};
#pragma unroll
            for (int j = 0; j < 4; ++j) {
                const int b = bc * 4 + j;
#pragma unroll
                for (int a = 0; a < 16; ++a) {
                    float tA = rA[a] * hAj[j];
                    float tB = rB[a] * hBj[j];
                    const float4* up = (const float4*)(Ut + (a * 16 + b) * 16);
#pragma unroll
                    for (int c4 = 0; c4 < 4; ++c4) {
                        float4 u = up[c4];
                        sA[4*c4+0] += u.x * tA; sA[4*c4+1] += u.y * tA;
                        sA[4*c4+2] += u.z * tA; sA[4*c4+3] += u.w * tA;
                        sB[4*c4+0] += u.x * tB; sB[4*c4+1] += u.y * tB;
                        sB[4*c4+2] += u.z * tB; sB[4*c4+3] += u.w * tB;
                    }
                }
            }
        }
#pragma unroll
        for (int c = 0; c < 16; ++c) { rA[c] = sA[c]; rB[c] = sB[c]; }
    }

    // ---- output: o[c] = sum_a Uo[a,c] * r[a] ----
    float oA[16], oB[16];
#pragma unroll
    for (int c = 0; c < 16; ++c) { oA[c] = 0.f; oB[c] = 0.f; }
#pragma unroll
    for (int a = 0; a < 16; ++a) {
#pragma unroll
        for (int c4 = 0; c4 < 4; ++c4) {
            float4 u = ((const float4*)(Uo + a * 16))[c4];
            oA[4*c4+0] += u.x * rA[a]; oA[4*c4+1] += u.y * rA[a];
            oA[4*c4+2] += u.z * rA[a]; oA[4*c4+3] += u.w * rA[a];
            oB[4*c4+0] += u.x * rB[a]; oB[4*c4+1] += u.y * rB[a];
            oB[4*c4+2] += u.z * rB[a]; oB[4*c4+3] += u.w * rB[a];
        }
    }
    if (nA < n) {
        float4* po = (float4*)(out + (size_t)nA * 16);
#pragma unroll
        for (int c4 = 0; c4 < 4; ++c4)
            po[c4] = make_float4(oA[4*c4+0], oA[4*c4+1], oA[4*c4+2], oA[4*c4+3]);
    }
    if (nB < n) {
        float4* po = (float4*)(out + (size_t)nB * 16);
#pragma unroll
        for (int c4 = 0; c4 < 4; ++c4)
            po[c4] = make_float4(oB[4*c4+0], oB[4*c4+1], oB[4*c4+2], oB[4*c4+3]);
    }
}

extern "C" void kernel_launch(void* const* d_in, const int* in_sizes, int n_in,
                              void* d_out, int out_size, void* d_ws, size_t ws_size,
                              hipStream_t stream) {
    const float* ns = (const float*)d_in[0];
    const float* U0 = (const float*)d_in[1];
    const float* Ur = (const float*)d_in[2];
    const float* Uo = (const float*)d_in[3];
    float* out = (float*)d_out;
    const int n = in_sizes[0] / (DEGREE * 16);
    const int blocks = (n + 511) / 512;
    tt_kernel<<<blocks, 256, 0, stream>>>(ns, U0, Ur, Uo, out, n);
}

// Round 2
// 1180.840 us; speedup vs baseline: 1.4362x; 1.4362x over previous
//
#include <hip/hip_runtime.h>

#define NSTEP 9

typedef __attribute__((ext_vector_type(8)))  __bf16 bf16x8;
typedef __attribute__((ext_vector_type(8)))  short  short8;
typedef __attribute__((ext_vector_type(4)))  float  floatx4;

// bf16 round-to-nearest (half-up in magnitude; tie bias negligible)
__device__ __forceinline__ unsigned short bf_hi(float x) {
    unsigned u = __float_as_uint(x);
    return (unsigned short)((u + 0x8000u) >> 16);
}
__device__ __forceinline__ float bf_hi_f(float x) {
    unsigned u = __float_as_uint(x);
    return __uint_as_float((u + 0x8000u) & 0xFFFF0000u);
}
__device__ __forceinline__ unsigned short bf_lo(float x) {
    return bf_hi(x - bf_hi_f(x));
}

__device__ __forceinline__ floatx4 mfma16(bf16x8 a, bf16x8 b, floatx4 c) {
    return __builtin_amdgcn_mfma_f32_16x16x32_bf16(a, b, c, 0, 0, 0);
}
__device__ __forceinline__ bf16x8 cvt(short8 s) {
    return __builtin_bit_cast(bf16x8, s);
}

// ---------------- prep: pack U0/U_rest into MFMA A-fragment layout ----------
// ws layout (short8 units):
//   [0..64)                     : U0 frag  (k<16 -> hi(U0[k][c]), k>=16 -> lo(U0[k-16][c]))
//   [64 + (t*16 + ki*2+v)*64+L) : step t, k-block ki, v=0 hi / v=1 lo
// A-frag element (lane L=(q,c), j): U[a][b][c], a=4q+(ki>>1), b=8(ki&1)+j
__global__ void prep_kernel(const float* __restrict__ U0,
                            const float* __restrict__ Ur,
                            short8* __restrict__ ws)
{
    const int fb   = blockIdx.x;    // 0..144
    const int lane = threadIdx.x;   // 0..63
    const int q = lane >> 4, c = lane & 15;
    short8 v;
    if (fb == 0) {
#pragma unroll
        for (int j = 0; j < 8; ++j) {
            int k = 8 * q + j;
            int b = (k < 16) ? k : (k - 16);
            float u = U0[b * 16 + c];
            v[j] = (short)((k < 16) ? bf_hi(u) : bf_lo(u));
        }
        ws[lane] = v;
    } else {
        int idx = fb - 1;            // 0..143
        int t   = idx >> 4;
        int r   = idx & 15;          // ki*2 + var
        int ki  = r >> 1, var = r & 1;
        int a   = 4 * q + (ki >> 1);
        int b0  = 8 * (ki & 1);
#pragma unroll
        for (int j = 0; j < 8; ++j) {
            float u = Ur[((t * 16 + a) * 16 + (b0 + j)) * 16 + c];
            v[j] = (short)(var == 0 ? bf_hi(u) : bf_lo(u));
        }
        ws[64 + idx * 64 + lane] = v;
    }
}

// ---------------- main ----------------
// Wave = 32 nodes (2 MFMA col-groups of 16). Lane (q,nn): holds ris[c=4q+reg]
// of its node in the accumulator. Recurrence lives entirely in the MFMA chain.
__global__ __launch_bounds__(256) void tt_main(
    const float*  __restrict__ ns,    // (n,10,16)
    const short8* __restrict__ Upk,   // packed U in ws
    const float*  __restrict__ Uo,    // (16,16)
    float*        __restrict__ out,   // (n,16)
    int n)
{
    const int lane = threadIdx.x & 63;
    const int wv   = threadIdx.x >> 6;
    const int q    = lane >> 4;
    const int nn   = lane & 15;
    const int nb   = blockIdx.x * 128 + wv * 32;
    const int n0   = nb + nn;
    const int n1   = nb + 16 + nn;
    const int c0   = (n0 < n) ? n0 : 0;
    const int c1   = (n1 < n) ? n1 : 0;
    const float* g0 = ns + (size_t)c0 * 160;
    const float* g1 = ns + (size_t)c1 * 160;

    floatx4 acc0, acc1;

    // ---- stage 0: ris0 = U0^T h0 via 2 MFMAs (full hi/lo split) ----
    {
        bf16x8 a0 = cvt(Upk[lane]);
        const int o = (q & 1) * 2;            // which 8 h0 values this lane supplies
        float4 x0 = ((const float4*)g0)[o], y0 = ((const float4*)g0)[o + 1];
        float4 x1 = ((const float4*)g1)[o], y1 = ((const float4*)g1)[o + 1];
        float h0a[8] = {x0.x,x0.y,x0.z,x0.w,y0.x,y0.y,y0.z,y0.w};
        float h0b[8] = {x1.x,x1.y,x1.z,x1.w,y1.x,y1.y,y1.z,y1.w};
        short8 bh0, bl0, bh1, bl1;
#pragma unroll
        for (int j = 0; j < 8; ++j) {
            bh0[j] = (short)bf_hi(h0a[j]); bl0[j] = (short)bf_lo(h0a[j]);
            bh1[j] = (short)bf_hi(h0b[j]); bl1[j] = (short)bf_lo(h0b[j]);
        }
        floatx4 z = {0.f, 0.f, 0.f, 0.f};
        acc0 = mfma16(a0, cvt(bh0), z);
        acc0 = mfma16(a0, cvt(bl0), acc0);
        acc1 = mfma16(a0, cvt(bh1), z);
        acc1 = mfma16(a0, cvt(bl1), acc1);
    }

    // ---- 9 bilinear steps, recurrence in the MFMA accumulator ----
#pragma unroll 1
    for (int t = 0; t < NSTEP; ++t) {
        const float4* h40 = (const float4*)(g0 + (t + 1) * 16);
        const float4* h41 = (const float4*)(g1 + (t + 1) * 16);
        float4 A0 = h40[0], A1 = h40[1], A2 = h40[2], A3 = h40[3];
        float4 B0 = h41[0], B1 = h41[1], B2 = h41[2], B3 = h41[3];
        float ha[16] = {A0.x,A0.y,A0.z,A0.w,A1.x,A1.y,A1.z,A1.w,
                        A2.x,A2.y,A2.z,A2.w,A3.x,A3.y,A3.z,A3.w};
        float hb[16] = {B0.x,B0.y,B0.z,B0.w,B1.x,B1.y,B1.z,B1.w,
                        B2.x,B2.y,B2.z,B2.w,B3.x,B3.y,B3.z,B3.w};

        const short8* ub = Upk + 64 + (size_t)t * 1024;
        floatx4 na = {0.f,0.f,0.f,0.f};
        floatx4 nbk = {0.f,0.f,0.f,0.f};
#pragma unroll
        for (int ki = 0; ki < 8; ++ki) {
            bf16x8 uh = cvt(ub[(ki * 2 + 0) * 64 + lane]);
            bf16x8 ul = cvt(ub[(ki * 2 + 1) * 64 + lane]);
            const float r0 = acc0[ki >> 1];
            const float r1 = acc1[ki >> 1];
            const int   b0 = 8 * (ki & 1);
            short8 wh0, wl0, wh1, wl1;
#pragma unroll
            for (int j = 0; j < 8; ++j) {
                float w0 = r0 * ha[b0 + j];
                float w1 = r1 * hb[b0 + j];
                wh0[j] = (short)bf_hi(w0); wl0[j] = (short)bf_lo(w0);
                wh1[j] = (short)bf_hi(w1); wl1[j] = (short)bf_lo(w1);
            }
            // U*w ~= U_hi*w_hi + U_hi*w_lo + U_lo*w_hi   (lo*lo ~ 2^-18, dropped)
            na  = mfma16(uh, cvt(wh0), na);
            na  = mfma16(uh, cvt(wl0), na);
            na  = mfma16(ul, cvt(wh0), na);
            nbk = mfma16(uh, cvt(wh1), nbk);
            nbk = mfma16(uh, cvt(wl1), nbk);
            nbk = mfma16(ul, cvt(wh1), nbk);
        }
        acc0 = na;
        acc1 = nbk;
    }

    // ---- output: out[n,c'] = sum_c Uo[c,c'] * ris[c]  (VALU + quad reduce) ----
    float po0[16], po1[16];
#pragma unroll
    for (int cc = 0; cc < 16; ++cc) { po0[cc] = 0.f; po1[cc] = 0.f; }
#pragma unroll
    for (int r = 0; r < 4; ++r) {
        const float* urow = Uo + (4 * q + r) * 16;
        float rv0 = acc0[r];
        float rv1 = acc1[r];
#pragma unroll
        for (int cc = 0; cc < 16; ++cc) {
            float u = urow[cc];
            po0[cc] += u * rv0;
            po1[cc] += u * rv1;
        }
    }
#pragma unroll
    for (int cc = 0; cc < 16; ++cc) {
        po0[cc] += __shfl_xor(po0[cc], 16, 64);
        po0[cc] += __shfl_xor(po0[cc], 32, 64);
        po1[cc] += __shfl_xor(po1[cc], 16, 64);
        po1[cc] += __shfl_xor(po1[cc], 32, 64);
    }
    if (n0 < n) {
        float4 sv;
        sv.x = q==0 ? po0[0] : q==1 ? po0[4] : q==2 ? po0[8]  : po0[12];
        sv.y = q==0 ? po0[1] : q==1 ? po0[5] : q==2 ? po0[9]  : po0[13];
        sv.z = q==0 ? po0[2] : q==1 ? po0[6] : q==2 ? po0[10] : po0[14];
        sv.w = q==0 ? po0[3] : q==1 ? po0[7] : q==2 ? po0[11] : po0[15];
        ((float4*)(out + (size_t)n0 * 16))[q] = sv;
    }
    if (n1 < n) {
        float4 sv;
        sv.x = q==0 ? po1[0] : q==1 ? po1[4] : q==2 ? po1[8]  : po1[12];
        sv.y = q==0 ? po1[1] : q==1 ? po1[5] : q==2 ? po1[9]  : po1[13];
        sv.z = q==0 ? po1[2] : q==1 ? po1[6] : q==2 ? po1[10] : po1[14];
        sv.w = q==0 ? po1[3] : q==1 ? po1[7] : q==2 ? po1[11] : po1[15];
        ((float4*)(out + (size_t)n1 * 16))[q] = sv;
    }
}

extern "C" void kernel_launch(void* const* d_in, const int* in_sizes, int n_in,
                              void* d_out, int out_size, void* d_ws, size_t ws_size,
                              hipStream_t stream) {
    const float* ns = (const float*)d_in[0];
    const float* U0 = (const float*)d_in[1];
    const float* Ur = (const float*)d_in[2];
    const float* Uo = (const float*)d_in[3];
    float* out = (float*)d_out;
    const int n = in_sizes[0] / 160;

    short8* wsv = (short8*)d_ws;
    prep_kernel<<<145, 64, 0, stream>>>(U0, Ur, wsv);

    const int blocks = (n + 127) / 128;
    tt_main<<<blocks, 256, 0, stream>>>(ns, wsv, Uo, out, n);
}